// Round 2
// baseline (416.756 us; speedup 1.0000x reference)
//
#include <hip/hip_runtime.h>
#include <hip/hip_bf16.h>
#include <cstdint>
#include <cstddef>

// ---------------------------------------------------------------------------
// FastARAttention fused pipeline, bf16-MFMA path.
// B=2 S=2048 H=2048 NH=16 NKV=8 D=128, THETA=1e4, EPS=1e-6, SCALE=D^-0.5
// ---------------------------------------------------------------------------

typedef __attribute__((ext_vector_type(8))) short bf16x8;
typedef __attribute__((ext_vector_type(4))) float f32x4;

#define B_ 2
#define S_ 2048
#define H_ 2048
#define NH_ 16
#define NKV_ 8
#define D_ 128
#define BS_ 4096          // B*S tokens
#define QKVO_ 4096        // NH*D + 2*NKV*D

__device__ __forceinline__ unsigned short f2bf(float f) {
  union { float f; unsigned u; } v; v.f = f;
  unsigned u = v.u;
  u += 0x7fffu + ((u >> 16) & 1u);   // RNE
  return (unsigned short)(u >> 16);
}

__device__ __forceinline__ void gload_lds16(const void* g, void* l) {
  __builtin_amdgcn_global_load_lds(
      (const __attribute__((address_space(1))) unsigned int*)g,
      (__attribute__((address_space(3))) unsigned int*)l, 16, 0, 0);
}

// ---------------------------------------------------------------------------
// fp32 -> bf16 convert, vectorized float4 -> ushort4
// ---------------------------------------------------------------------------
__global__ void k_f32_to_bf16(const float* __restrict__ x,
                              unsigned short* __restrict__ y, int n4) {
  int i = blockIdx.x * blockDim.x + threadIdx.x;
  if (i >= n4) return;
  float4 v = ((const float4*)x)[i];
  ushort4 o;
  o.x = f2bf(v.x); o.y = f2bf(v.y); o.z = f2bf(v.z); o.w = f2bf(v.w);
  ((ushort4*)y)[i] = o;
}

// ---------------------------------------------------------------------------
// bf16 GEMM: C[M,N] fp32 = A[M,K] * B[N,K]^T  (both row-major over [*,K])
// 128x128 tile, BK=32, 4 waves (2x2 of 64x64), 16x16x32 MFMA,
// double-buffered global_load_lds (16B) with XOR swizzle:
//   64B rows -> byte ^= ((row>>1)&3)<<4  => 2 lanes/16B-slot on ds_read = free
// ---------------------------------------------------------------------------
#define BM 128
#define BN 128
#define BK 32

__global__ __launch_bounds__(256, 2) void k_gemm_bf16(
    const unsigned short* __restrict__ A, const unsigned short* __restrict__ Bm,
    float* __restrict__ C, int M, int N, int K) {
  __shared__ __align__(16) char lds[2][2][BM * BK * 2];  // [buf][A/B][8KB]

  int nwg = gridDim.x;
  int bid = blockIdx.x;
  int cpx = nwg >> 3;                       // nwg divisible by 8 in all launches
  int swz = (bid & 7) * cpx + (bid >> 3);   // bijective XCD swizzle
  int nbn = N / BN;
  int bm = swz / nbn, bn = swz % nbn;

  int tid = threadIdx.x;
  int lane = tid & 63, w = tid >> 6;
  int wr = w >> 1, wc = w & 1;
  int lq = lane & 15, lk = lane >> 4;

  const unsigned short* Abase = A + (size_t)bm * BM * K;
  const unsigned short* Bbase = Bm + (size_t)bn * BN * K;

  f32x4 acc[4][4] = {};
  int nt = K / BK;

  auto stage = [&](int buf, int t) {
#pragma unroll
    for (int j = 0; j < 2; ++j) {
      int s = (tid + j * 256) * 16;           // linear 16B slot (per-wave: base+lane*16)
      int row = s >> 6;                       // 64B per row (32 bf16)
      int cb = s & 48;
      int cs = cb ^ (((row >> 1) & 3) << 4);  // inverse swizzle on SOURCE (rule #21)
      const char* ga = (const char*)(Abase + (size_t)row * K + t * BK) + cs;
      const char* gb = (const char*)(Bbase + (size_t)row * K + t * BK) + cs;
      gload_lds16(ga, &lds[buf][0][s]);
      gload_lds16(gb, &lds[buf][1][s]);
    }
  };

  stage(0, 0);
  __syncthreads();

  int cur = 0;
  for (int t = 0; t < nt; ++t) {
    if (t + 1 < nt) stage(cur ^ 1, t + 1);
    bf16x8 af[4], bfr[4];
#pragma unroll
    for (int m = 0; m < 4; ++m) {
      int row = wr * 64 + m * 16 + lq;
      int addr = row * 64 + ((lk * 16) ^ (((row >> 1) & 3) << 4));
      af[m] = *(const bf16x8*)(&lds[cur][0][addr]);
    }
#pragma unroll
    for (int n = 0; n < 4; ++n) {
      int row = wc * 64 + n * 16 + lq;
      int addr = row * 64 + ((lk * 16) ^ (((row >> 1) & 3) << 4));
      bfr[n] = *(const bf16x8*)(&lds[cur][1][addr]);
    }
#pragma unroll
    for (int m = 0; m < 4; ++m)
#pragma unroll
      for (int n = 0; n < 4; ++n)
        acc[m][n] = __builtin_amdgcn_mfma_f32_16x16x32_bf16(af[m], bfr[n], acc[m][n], 0, 0, 0);
    __syncthreads();   // drains vmcnt(0): next buffer staged & this buffer free
    cur ^= 1;
  }

#pragma unroll
  for (int m = 0; m < 4; ++m) {
    int row0 = bm * BM + wr * 64 + m * 16 + lk * 4;
#pragma unroll
    for (int n = 0; n < 4; ++n) {
      int col = bn * BN + wc * 64 + n * 16 + lq;
#pragma unroll
      for (int r = 0; r < 4; ++r)
        C[(size_t)(row0 + r) * N + col] = acc[m][n][r];
    }
  }
}

// ---------------------------------------------------------------------------
// Fused per-head RMSNorm + GPT-J RoPE for q and k sections of qkv.
// One 64-lane wave per (token, head-slot); lane i owns rotation pair (2i,2i+1).
// slots 0..15 = q heads, 16..23 = k heads. 4 waves per 256-thread block.
// Outputs: Qb [B][NH][S][D] bf16, Kb [B][NKV][S][D] bf16.
// ---------------------------------------------------------------------------
__global__ void k_norm_rope(const float* __restrict__ qkv,
                            const int* __restrict__ pos,
                            const float* __restrict__ qw,
                            const float* __restrict__ kw,
                            unsigned short* __restrict__ Qb,
                            unsigned short* __restrict__ Kb) {
  int g = blockIdx.x * 4 + (threadIdx.x >> 6);   // global (token,slot) id
  int lane = threadIdx.x & 63;
  int t = g / 24;
  int slot = g % 24;
  bool isq = slot < 16;
  int h = isq ? slot : slot - 16;
  int off = isq ? h * D_ : NH_ * D_ + h * D_;
  const float* w = isq ? qw : kw;

  float2 x = *(const float2*)(qkv + (size_t)t * QKVO_ + off + lane * 2);
  float ss = x.x * x.x + x.y * x.y;
#pragma unroll
  for (int o = 1; o < 64; o <<= 1) ss += __shfl_xor(ss, o);
  float inv = rsqrtf(ss * (1.0f / 128.0f) + 1e-6f);
  float2 wv = *(const float2*)(w + lane * 2);
  float x1 = x.x * inv * wv.x;
  float x2 = x.y * inv * wv.y;

  float p = (float)pos[t];
  // inv_freq = theta^(-2i/D) = 2^(-2i * log2(theta)/D)
  float invf = exp2f(-(float)(lane * 2) * (13.287712379549449f / 128.0f));
  float ang = p * invf;
  float sn, cs;
  sincosf(ang, &sn, &cs);
  float y1 = x1 * cs - x2 * sn;
  float y2 = x2 * cs + x1 * sn;

  int b = t >> 11;           // /S_
  int sq = t & (S_ - 1);
  size_t o_;
  unsigned short* dst;
  if (isq) { o_ = (((size_t)b * NH_ + h) * S_ + sq) * D_ + lane * 2; dst = Qb; }
  else     { o_ = (((size_t)b * NKV_ + h) * S_ + sq) * D_ + lane * 2; dst = Kb; }
  ushort2 ov; ov.x = f2bf(y1); ov.y = f2bf(y2);
  *(ushort2*)(dst + o_) = ov;
}

// ---------------------------------------------------------------------------
// V: convert fp32 section of qkv -> bf16, transposed to Vt [B][NKV][D][S]
// (so attention can stage Vt tiles [D][kv] with linear global_load_lds).
// Tile: 64 tokens x 128 d, via LDS.
// ---------------------------------------------------------------------------
__global__ void k_v_transpose(const float* __restrict__ qkv,
                              unsigned short* __restrict__ Vt) {
  __shared__ unsigned short tile[128][72];
  int bidx = blockIdx.x;
  int st = bidx & 31;
  int kh = (bidx >> 5) & 7;
  int b = bidx >> 8;
  int s0 = st * 64;
  int tid = threadIdx.x;
#pragma unroll
  for (int i = 0; i < 8; ++i) {
    int idx = tid + i * 256;          // 0..2047
    int row = idx >> 5, c4 = idx & 31;
    float4 v = *(const float4*)(qkv + ((size_t)(b * S_ + s0 + row)) * QKVO_ +
                                (NH_ + NKV_) * D_ + kh * D_ + c4 * 4);
    tile[c4 * 4 + 0][row] = f2bf(v.x);
    tile[c4 * 4 + 1][row] = f2bf(v.y);
    tile[c4 * 4 + 2][row] = f2bf(v.z);
    tile[c4 * 4 + 3][row] = f2bf(v.w);
  }
  __syncthreads();
#pragma unroll
  for (int i = 0; i < 8; ++i) {
    int idx = tid + i * 256;          // 0..2047
    int d = idx >> 4, c4 = idx & 15;
    ushort4 o;
    o.x = tile[d][c4 * 4 + 0]; o.y = tile[d][c4 * 4 + 1];
    o.z = tile[d][c4 * 4 + 2]; o.w = tile[d][c4 * 4 + 3];
    *(ushort4*)(Vt + ((((size_t)b * NKV_ + kh) * D_ + d) * S_) + s0 + c4 * 4) = o;
  }
}

// ---------------------------------------------------------------------------
// Causal GQA flash attention. QBLK=128 (4 waves x 32 rows), KVB=64.
// K LDS [kv][d] (256B rows), Vt LDS [d][kv] (128B rows), both XOR-swizzled
// byte ^= ((row&7)<<4); P wave-private LDS [32][kv] (128B rows, same swizzle).
// Online softmax in registers over 16-lane groups. Output bf16 [BS][NH*D].
//
// Load balance: 512 blocks, 2 resident/CU (80KB LDS). Linear ids x and x+256
// co-locate on a CU (round-robin dispatch), so decode qt mirrored on bit 8:
// per-CU pair does (2(15-k)+2) + (2k+2) = 34 KV-tiles, constant.
// ---------------------------------------------------------------------------
#define QBLK 128
#define KVB 64

__global__ __launch_bounds__(256, 2) void k_attn(
    const unsigned short* __restrict__ Qb, const unsigned short* __restrict__ Kb,
    const unsigned short* __restrict__ Vt, unsigned short* __restrict__ Ob) {
  __shared__ __align__(16) char Ks[2][KVB * D_ * 2];   // 16KB x2
  __shared__ __align__(16) char Vs[2][D_ * KVB * 2];   // 16KB x2
  __shared__ __align__(16) char Ps[4][32 * KVB * 2];   // 4KB per wave

  int x = blockIdx.x;                    // 0..511
  int u = x & 255;
  int hi = x >> 8;
  int k_ = u & 15;
  int qt = hi ? k_ : 15 - k_;            // mirror pairing across bit 8
  int h = u >> 4;                        // 0..15
  int b = hi;                            // B_ == 2
  int kvh = h >> 1;                      // G = NH/NKV = 2
  int q0 = qt * QBLK;
  int tid = threadIdx.x, lane = tid & 63, w = tid >> 6;
  int lq = lane & 15, lk = lane >> 4;

  const unsigned short* Qhead = Qb + ((size_t)b * NH_ + h) * S_ * D_;
  const unsigned short* Khead = Kb + ((size_t)b * NKV_ + kvh) * S_ * D_;
  const unsigned short* Vthead = Vt + ((size_t)b * NKV_ + kvh) * D_ * S_;

  // Q fragments in registers: rows w*32 + m*16 + lq, d = ks*32 + lk*8
  bf16x8 qf[2][4];
#pragma unroll
  for (int m = 0; m < 2; ++m)
#pragma unroll
    for (int ks = 0; ks < 4; ++ks)
      qf[m][ks] = *(const bf16x8*)(Qhead +
          (size_t)(q0 + w * 32 + m * 16 + lq) * D_ + ks * 32 + lk * 8);

  f32x4 o_acc[2][8] = {};
  float mrow[2][4], lrow[2][4];
#pragma unroll
  for (int m = 0; m < 2; ++m)
#pragma unroll
    for (int r = 0; r < 4; ++r) { mrow[m][r] = -1e30f; lrow[m][r] = 0.0f; }

  int ntile = q0 / KVB + 2;

  auto stageKV = [&](int buf, int t) {
    int kv0 = t * KVB;
#pragma unroll
    for (int j = 0; j < 4; ++j) {
      int s = (tid + j * 256) * 16;
      {  // K tile: row = kv (256B), inverse swizzle on source col
        int row = s >> 8, cb = s & 255;
        int cs = cb ^ ((row & 7) << 4);
        const char* g = (const char*)(Khead + (size_t)(kv0 + row) * D_) + cs;
        gload_lds16(g, &Ks[buf][s]);
      }
      {  // Vt tile: row = d (128B)
        int row = s >> 7, cb = s & 127;
        int cs = cb ^ ((row & 7) << 4);
        const char* g = (const char*)(Vthead + (size_t)row * S_ + kv0) + cs;
        gload_lds16(g, &Vs[buf][s]);
      }
    }
  };

  stageKV(0, 0);
  __syncthreads();

  const float c1 = 0.08838834764831845f * 1.4426950408889634f;  // SCALE*log2e

  int cur = 0;
  for (int t = 0; t < ntile; ++t) {
    if (t + 1 < ntile) stageKV(cur ^ 1, t + 1);
    int kv0 = t * KVB;

    // ---- QK^T ----
    f32x4 sc[2][4] = {};
#pragma unroll
    for (int ks = 0; ks < 4; ++ks) {
      bf16x8 kf[4];
#pragma unroll
      for (int n = 0; n < 4; ++n) {
        int row = n * 16 + lq;
        int addr = row * 256 + ((ks * 64 + lk * 16) ^ ((row & 7) << 4));
        kf[n] = *(const bf16x8*)(&Ks[cur][addr]);
      }
#pragma unroll
      for (int m = 0; m < 2; ++m)
#pragma unroll
        for (int n = 0; n < 4; ++n)
          sc[m][n] = __builtin_amdgcn_mfma_f32_16x16x32_bf16(qf[m][ks], kf[n], sc[m][n], 0, 0, 0);
    }

    // ---- online softmax ----
    bool diag = (kv0 + KVB > q0);
#pragma unroll
    for (int m = 0; m < 2; ++m) {
      float pm[4][4];   // [n][r]
      float corr[4];
#pragma unroll
      for (int r = 0; r < 4; ++r) {
        int qg = q0 + w * 32 + m * 16 + lk * 4 + r;
        float vmax = -1e30f;
        float sv[4];
#pragma unroll
        for (int n = 0; n < 4; ++n) {
          float xv = sc[m][n][r] * c1;
          if (diag && (kv0 + n * 16 + lq > qg)) xv = -1e30f;
          sv[n] = xv;
          vmax = fmaxf(vmax, xv);
        }
#pragma unroll
        for (int o = 1; o < 16; o <<= 1) vmax = fmaxf(vmax, __shfl_xor(vmax, o));
        float mnew = fmaxf(mrow[m][r], vmax);
        float cr = exp2f(mrow[m][r] - mnew);
        mrow[m][r] = mnew;
        float rs = 0.0f;
#pragma unroll
        for (int n = 0; n < 4; ++n) {
          float pv = exp2f(sv[n] - mnew);
          pm[n][r] = pv;
          rs += pv;
        }
#pragma unroll
        for (int o = 1; o < 16; o <<= 1) rs += __shfl_xor(rs, o);
        lrow[m][r] = lrow[m][r] * cr + rs;
        corr[r] = cr;
      }
#pragma unroll
      for (int nd = 0; nd < 8; ++nd)
#pragma unroll
        for (int r = 0; r < 4; ++r) o_acc[m][nd][r] *= corr[r];
      // P -> wave-private LDS (bf16), swizzled; same-wave RAW => compiler
      // orders via lgkmcnt, no barrier needed
#pragma unroll
      for (int n = 0; n < 4; ++n)
#pragma unroll
        for (int r = 0; r < 4; ++r) {
          int qlocal = m * 16 + lk * 4 + r;
          int kb = (n * 16 + lq) * 2;
          int addr = qlocal * 128 + (kb ^ ((qlocal & 7) << 4));
          *(unsigned short*)(&Ps[w][addr]) = f2bf(pm[n][r]);
        }
    }

    // ---- PV ----
#pragma unroll
    for (int ks = 0; ks < 2; ++ks) {
      bf16x8 pa[2];
#pragma unroll
      for (int m = 0; m < 2; ++m) {
        int row = m * 16 + lq;
        int addr = row * 128 + ((ks * 64 + lk * 16) ^ ((row & 7) << 4));
        pa[m] = *(const bf16x8*)(&Ps[w][addr]);
      }
#pragma unroll
      for (int nd = 0; nd < 8; ++nd) {
        int row = nd * 16 + lq;
        int addr = row * 128 + ((ks * 64 + lk * 16) ^ ((row & 7) << 4));
        bf16x8 vf = *(const bf16x8*)(&Vs[cur][addr]);
#pragma unroll
        for (int m = 0; m < 2; ++m)
          o_acc[m][nd] = __builtin_amdgcn_mfma_f32_16x16x32_bf16(pa[m], vf, o_acc[m][nd], 0, 0, 0);
      }
    }
    __syncthreads();
    cur ^= 1;
  }

  // ---- epilogue: O/l -> bf16 [BS][NH*D] ----
#pragma unroll
  for (int m = 0; m < 2; ++m)
#pragma unroll
    for (int r = 0; r < 4; ++r) {
      float rl = 1.0f / lrow[m][r];
      int qg = q0 + w * 32 + m * 16 + lk * 4 + r;
      size_t base = ((size_t)b * S_ + qg) * (NH_ * D_) + h * D_;
#pragma unroll
      for (int nd = 0; nd < 8; ++nd)
        Ob[base + nd * 16 + lq] = f2bf(o_acc[m][nd][r] * rl);
    }
}

// ---------------------------------------------------------------------------
extern "C" void kernel_launch(void* const* d_in, const int* in_sizes, int n_in,
                              void* d_out, int out_size, void* d_ws, size_t ws_size,
                              hipStream_t stream) {
  const float* hs    = (const float*)d_in[0];
  const int*   pos   = (const int*)d_in[1];
  const float* w_qkv = (const float*)d_in[2];
  const float* w_o   = (const float*)d_in[3];
  const float* qw    = (const float*)d_in[4];
  const float* kw    = (const float*)d_in[5];
  float* out = (float*)d_out;

  char* ws = (char*)d_ws;
  unsigned short* Xbf  = (unsigned short*)ws;                         // 16 MB
  unsigned short* Wqbf = Xbf + (size_t)BS_ * H_;                      // 16 MB
  unsigned short* Wobf = Wqbf + (size_t)QKVO_ * H_;                   // 8 MB
  float* qkv = (float*)(Wobf + (size_t)H_ * (NH_ * D_));              // 64 MB
  unsigned short* Qb  = (unsigned short*)(qkv + (size_t)BS_ * QKVO_); // 16 MB
  unsigned short* Kb  = Qb + (size_t)B_ * NH_ * S_ * D_;              // 8 MB
  unsigned short* Vtb = Kb + (size_t)B_ * NKV_ * S_ * D_;             // 8 MB
  unsigned short* Ab  = Vtb + (size_t)B_ * NKV_ * S_ * D_;            // 16 MB

  // 1. converts
  k_f32_to_bf16<<<(BS_ * H_ / 4) / 256, 256, 0, stream>>>(hs, Xbf, BS_ * H_ / 4);
  k_f32_to_bf16<<<(QKVO_ * H_ / 4) / 256, 256, 0, stream>>>(w_qkv, Wqbf, QKVO_ * H_ / 4);
  k_f32_to_bf16<<<(H_ * NH_ * D_ / 4) / 256, 256, 0, stream>>>(w_o, Wobf, H_ * NH_ * D_ / 4);

  // 2. QKV GEMM: [4096,2048] x [4096,2048]^T -> [4096,4096] fp32
  k_gemm_bf16<<<(BS_ / BM) * (QKVO_ / BN), 256, 0, stream>>>(
      Xbf, Wqbf, qkv, BS_, QKVO_, H_);

  // 3. RMSNorm + RoPE for q,k
  k_norm_rope<<<BS_ * 24 / 4, 256, 0, stream>>>(qkv, pos, qw, kw, Qb, Kb);

  // 4. V convert+transpose
  k_v_transpose<<<B_ * NKV_ * (S_ / 64), 256, 0, stream>>>(qkv, Vtb);

  // 5. causal GQA flash attention (1D grid, mirror-balanced)
  k_attn<<<(S_ / QBLK) * NH_ * B_, 256, 0, stream>>>(Qb, Kb, Vtb, Ab);

  // 6. output GEMM: [4096,2048] x [2048,2048]^T -> d_out fp32
  k_gemm_bf16<<<(BS_ / BM) * (H_ / BN), 256, 0, stream>>>(
      Ab, Wobf, out, BS_, H_, H_);
}

// Round 4
// 377.556 us; speedup vs baseline: 1.1038x; 1.1038x over previous
//
#include <hip/hip_runtime.h>
#include <hip/hip_bf16.h>
#include <cstdint>
#include <cstddef>

// ---------------------------------------------------------------------------
// FastARAttention fused pipeline, bf16-MFMA path.
// B=2 S=2048 H=2048 NH=16 NKV=8 D=128, THETA=1e4, EPS=1e-6, SCALE=D^-0.5
// ---------------------------------------------------------------------------

typedef __attribute__((ext_vector_type(8))) short bf16x8;
typedef __attribute__((ext_vector_type(4))) float f32x4;

#define B_ 2
#define S_ 2048
#define H_ 2048
#define NH_ 16
#define NKV_ 8
#define D_ 128
#define BS_ 4096          // B*S tokens
#define QKVO_ 4096        // NH*D + 2*NKV*D

__device__ __forceinline__ unsigned short f2bf(float f) {
  union { float f; unsigned u; } v; v.f = f;
  unsigned u = v.u;
  u += 0x7fffu + ((u >> 16) & 1u);   // RNE
  return (unsigned short)(u >> 16);
}

__device__ __forceinline__ unsigned cvt_pk_bf16(float lo, float hi) {
  unsigned r;
  asm("v_cvt_pk_bf16_f32 %0, %1, %2" : "=v"(r) : "v"(lo), "v"(hi));
  return r;
}

__device__ __forceinline__ void gload_lds16(const void* g, void* l) {
  __builtin_amdgcn_global_load_lds(
      (const __attribute__((address_space(1))) unsigned int*)g,
      (__attribute__((address_space(3))) unsigned int*)l, 16, 0, 0);
}

// ---------------------------------------------------------------------------
// fp32 -> bf16 convert, vectorized float4 -> ushort4
// ---------------------------------------------------------------------------
__global__ void k_f32_to_bf16(const float* __restrict__ x,
                              unsigned short* __restrict__ y, int n4) {
  int i = blockIdx.x * blockDim.x + threadIdx.x;
  if (i >= n4) return;
  float4 v = ((const float4*)x)[i];
  ushort4 o;
  o.x = f2bf(v.x); o.y = f2bf(v.y); o.z = f2bf(v.z); o.w = f2bf(v.w);
  ((ushort4*)y)[i] = o;
}

// ---------------------------------------------------------------------------
// bf16 GEMM: C[M,N] fp32 = A[M,K] * B[N,K]^T  (both row-major over [*,K])
// 128x128 tile, BK=32, 4 waves (2x2 of 64x64), 16x16x32 MFMA,
// double-buffered global_load_lds (16B) with XOR swizzle.
// ---------------------------------------------------------------------------
#define BM 128
#define BN 128
#define BK 32

__global__ __launch_bounds__(256, 2) void k_gemm_bf16(
    const unsigned short* __restrict__ A, const unsigned short* __restrict__ Bm,
    float* __restrict__ C, int M, int N, int K) {
  __shared__ __align__(16) char lds[2][2][BM * BK * 2];  // [buf][A/B][8KB]

  int nwg = gridDim.x;
  int bid = blockIdx.x;
  int cpx = nwg >> 3;                       // nwg divisible by 8 in all launches
  int swz = (bid & 7) * cpx + (bid >> 3);   // bijective XCD swizzle
  int nbn = N / BN;
  int bm = swz / nbn, bn = swz % nbn;

  int tid = threadIdx.x;
  int lane = tid & 63, w = tid >> 6;
  int wr = w >> 1, wc = w & 1;
  int lq = lane & 15, lk = lane >> 4;

  const unsigned short* Abase = A + (size_t)bm * BM * K;
  const unsigned short* Bbase = Bm + (size_t)bn * BN * K;

  f32x4 acc[4][4] = {};
  int nt = K / BK;

  auto stage = [&](int buf, int t) {
#pragma unroll
    for (int j = 0; j < 2; ++j) {
      int s = (tid + j * 256) * 16;           // linear 16B slot
      int row = s >> 6;                       // 64B per row (32 bf16)
      int cb = s & 48;
      int cs = cb ^ (((row >> 1) & 3) << 4);  // inverse swizzle on SOURCE
      const char* ga = (const char*)(Abase + (size_t)row * K + t * BK) + cs;
      const char* gb = (const char*)(Bbase + (size_t)row * K + t * BK) + cs;
      gload_lds16(ga, &lds[buf][0][s]);
      gload_lds16(gb, &lds[buf][1][s]);
    }
  };

  stage(0, 0);
  __syncthreads();

  int cur = 0;
  for (int t = 0; t < nt; ++t) {
    if (t + 1 < nt) stage(cur ^ 1, t + 1);
    bf16x8 af[4], bfr[4];
#pragma unroll
    for (int m = 0; m < 4; ++m) {
      int row = wr * 64 + m * 16 + lq;
      int addr = row * 64 + ((lk * 16) ^ (((row >> 1) & 3) << 4));
      af[m] = *(const bf16x8*)(&lds[cur][0][addr]);
    }
#pragma unroll
    for (int n = 0; n < 4; ++n) {
      int row = wc * 64 + n * 16 + lq;
      int addr = row * 64 + ((lk * 16) ^ (((row >> 1) & 3) << 4));
      bfr[n] = *(const bf16x8*)(&lds[cur][1][addr]);
    }
#pragma unroll
    for (int m = 0; m < 4; ++m)
#pragma unroll
      for (int n = 0; n < 4; ++n)
        acc[m][n] = __builtin_amdgcn_mfma_f32_16x16x32_bf16(af[m], bfr[n], acc[m][n], 0, 0, 0);
    __syncthreads();
    cur ^= 1;
  }

#pragma unroll
  for (int m = 0; m < 4; ++m) {
    int row0 = bm * BM + wr * 64 + m * 16 + lk * 4;
#pragma unroll
    for (int n = 0; n < 4; ++n) {
      int col = bn * BN + wc * 64 + n * 16 + lq;
#pragma unroll
      for (int r = 0; r < 4; ++r)
        C[(size_t)(row0 + r) * N + col] = acc[m][n][r];
    }
  }
}

// ---------------------------------------------------------------------------
// Fused per-head RMSNorm + GPT-J RoPE for q and k sections of qkv.
// ---------------------------------------------------------------------------
__global__ void k_norm_rope(const float* __restrict__ qkv,
                            const int* __restrict__ pos,
                            const float* __restrict__ qw,
                            const float* __restrict__ kw,
                            unsigned short* __restrict__ Qb,
                            unsigned short* __restrict__ Kb) {
  int g = blockIdx.x * 4 + (threadIdx.x >> 6);   // global (token,slot) id
  int lane = threadIdx.x & 63;
  int t = g / 24;
  int slot = g % 24;
  bool isq = slot < 16;
  int h = isq ? slot : slot - 16;
  int off = isq ? h * D_ : NH_ * D_ + h * D_;
  const float* w = isq ? qw : kw;

  float2 x = *(const float2*)(qkv + (size_t)t * QKVO_ + off + lane * 2);
  float ss = x.x * x.x + x.y * x.y;
#pragma unroll
  for (int o = 1; o < 64; o <<= 1) ss += __shfl_xor(ss, o);
  float inv = rsqrtf(ss * (1.0f / 128.0f) + 1e-6f);
  float2 wv = *(const float2*)(w + lane * 2);
  float x1 = x.x * inv * wv.x;
  float x2 = x.y * inv * wv.y;

  float p = (float)pos[t];
  float invf = exp2f(-(float)(lane * 2) * (13.287712379549449f / 128.0f));
  float ang = p * invf;
  float sn, cs;
  sincosf(ang, &sn, &cs);
  float y1 = x1 * cs - x2 * sn;
  float y2 = x2 * cs + x1 * sn;

  int b = t >> 11;           // /S_
  int sq = t & (S_ - 1);
  size_t o_;
  unsigned short* dst;
  if (isq) { o_ = (((size_t)b * NH_ + h) * S_ + sq) * D_ + lane * 2; dst = Qb; }
  else     { o_ = (((size_t)b * NKV_ + h) * S_ + sq) * D_ + lane * 2; dst = Kb; }
  ushort2 ov; ov.x = f2bf(y1); ov.y = f2bf(y2);
  *(ushort2*)(dst + o_) = ov;
}

// ---------------------------------------------------------------------------
// V: convert fp32 section of qkv -> bf16, transposed to Vt [B][NKV][D][S].
// ---------------------------------------------------------------------------
__global__ void k_v_transpose(const float* __restrict__ qkv,
                              unsigned short* __restrict__ Vt) {
  __shared__ unsigned short tile[128][72];
  int bidx = blockIdx.x;
  int st = bidx & 31;
  int kh = (bidx >> 5) & 7;
  int b = bidx >> 8;
  int s0 = st * 64;
  int tid = threadIdx.x;
#pragma unroll
  for (int i = 0; i < 8; ++i) {
    int idx = tid + i * 256;          // 0..2047
    int row = idx >> 5, c4 = idx & 31;
    float4 v = *(const float4*)(qkv + ((size_t)(b * S_ + s0 + row)) * QKVO_ +
                                (NH_ + NKV_) * D_ + kh * D_ + c4 * 4);
    tile[c4 * 4 + 0][row] = f2bf(v.x);
    tile[c4 * 4 + 1][row] = f2bf(v.y);
    tile[c4 * 4 + 2][row] = f2bf(v.z);
    tile[c4 * 4 + 3][row] = f2bf(v.w);
  }
  __syncthreads();
#pragma unroll
  for (int i = 0; i < 8; ++i) {
    int idx = tid + i * 256;          // 0..2047
    int d = idx >> 4, c4 = idx & 15;
    ushort4 o;
    o.x = tile[d][c4 * 4 + 0]; o.y = tile[d][c4 * 4 + 1];
    o.z = tile[d][c4 * 4 + 2]; o.w = tile[d][c4 * 4 + 3];
    *(ushort4*)(Vt + ((((size_t)b * NKV_ + kh) * D_ + d) * S_) + s0 + c4 * 4) = o;
  }
}

// ---------------------------------------------------------------------------
// Causal GQA flash attention — uniform-load blocks, swapped-QK^T softmax.
//
// Block = 512 threads (8 waves). Waves 0-3 own q-strip qt_hi=15-kk,
// waves 4-7 own q-strip qt_lo=kk (32 q-rows per wave). KV staged once per
// block to nt_max = 2*qt_hi+2 tiles; short-strip waves predicate off past
// their causal range. Per-block wall = (2k+2) full-rate + (30-4k) half-rate
// tile-times = constant ~17T for every block -> uniform makespan.
// Grid = 256 blocks = 1/CU (96 KB LDS). Block id: kk = x>>5 so blocks
// sharing (b,h) land on the same XCD (x mod 8 = bh&7) for K/V L2 reuse.
//
// Swapped QK^T: sc = mfma(K,Q) -> lane holds one q-column (q = m*16+lq),
// k in-lane (n*16+lk*4+r). Row-reduce = in-lane tree + 2 shfl_xor (16,32).
// P packed to LDS via v_cvt_pk_bf16_f32 + ds_write_b64 (8 writes/tile).
// Rescale factors cross softmax->output lane space via 4 shfl per m.
// ---------------------------------------------------------------------------
#define KVB 64

__global__ __launch_bounds__(512, 2) void k_attn(
    const unsigned short* __restrict__ Qb, const unsigned short* __restrict__ Kb,
    const unsigned short* __restrict__ Vt, unsigned short* __restrict__ Ob) {
  __shared__ __align__(16) char Ks[2][KVB * D_ * 2];   // 16KB x2
  __shared__ __align__(16) char Vs[2][D_ * KVB * 2];   // 16KB x2
  __shared__ __align__(16) char Ps[8][32 * KVB * 2];   // 4KB per wave

  int x = blockIdx.x;          // 0..255
  int kk = x >> 5;             // 0..7
  int bh = x & 31;
  int b = bh >> 4, h = bh & 15;
  int kvh = h >> 1;            // G = NH/NKV = 2

  int tid = threadIdx.x, lane = tid & 63, w = tid >> 6;
  int lq = lane & 15, lk = lane >> 4;
  int strip = w >> 2, wq = w & 3;
  int qt = strip ? kk : 15 - kk;
  int q0w = qt * 128 + wq * 32;           // this wave's first q row
  int nt_w = ((q0w + 31) >> 6) + 1;       // causal tile count for this wave
  int nt_max = 2 * (15 - kk) + 2;         // block staging span

  const unsigned short* Qhead = Qb + ((size_t)b * NH_ + h) * S_ * D_;
  const unsigned short* Khead = Kb + ((size_t)b * NKV_ + kvh) * S_ * D_;
  const unsigned short* Vthead = Vt + ((size_t)b * NKV_ + kvh) * D_ * S_;

  // Q fragments: rows q0w + m*16 + lq, d = ks*32 + lk*8
  bf16x8 qf[2][4];
#pragma unroll
  for (int m = 0; m < 2; ++m)
#pragma unroll
    for (int ks = 0; ks < 4; ++ks)
      qf[m][ks] = *(const bf16x8*)(Qhead +
          (size_t)(q0w + m * 16 + lq) * D_ + ks * 32 + lk * 8);

  f32x4 o_acc[2][8] = {};
  float mrow[2] = {-1e30f, -1e30f};
  float lrow[2] = {0.0f, 0.0f};

  auto stageKV = [&](int buf, int t) {
    int kv0 = t * KVB;
#pragma unroll
    for (int j = 0; j < 2; ++j) {
      int s = (tid + j * 512) * 16;
      {  // K tile: row = kv (256B rows), inverse swizzle on source col
        int row = s >> 8, cb = s & 255;
        int cs = cb ^ ((row & 7) << 4);
        const char* g = (const char*)(Khead + (size_t)(kv0 + row) * D_) + cs;
        gload_lds16(g, &Ks[buf][s]);
      }
      {  // Vt tile: row = d (128B rows)
        int rv = s >> 7, cv = s & 127;
        int cs = cv ^ ((rv & 7) << 4);
        const char* g = (const char*)(Vthead + (size_t)rv * S_ + kv0) + cs;
        gload_lds16(g, &Vs[buf][s]);
      }
    }
  };

  stageKV(0, 0);
  __syncthreads();

  const float c1 = 0.08838834764831845f * 1.4426950408889634f;  // SCALE*log2e

  int cur = 0;
  for (int t = 0; t < nt_max; ++t) {
    if (t + 1 < nt_max) stageKV(cur ^ 1, t + 1);
    if (t < nt_w) {
      int kv0 = t * KVB;

      // ---- QK^T (swapped: rows=k, cols=q) ----
      f32x4 sc[4][2] = {};
      __builtin_amdgcn_s_setprio(1);
#pragma unroll
      for (int ks = 0; ks < 4; ++ks) {
        bf16x8 kf[4];
#pragma unroll
        for (int n = 0; n < 4; ++n) {
          int row = n * 16 + lq;
          int addr = row * 256 + ((ks * 64 + lk * 16) ^ ((row & 7) << 4));
          kf[n] = *(const bf16x8*)(&Ks[cur][addr]);
        }
#pragma unroll
        for (int n = 0; n < 4; ++n)
#pragma unroll
          for (int m = 0; m < 2; ++m)
            sc[n][m] = __builtin_amdgcn_mfma_f32_16x16x32_bf16(kf[n], qf[m][ks], sc[n][m], 0, 0, 0);
      }
      __builtin_amdgcn_s_setprio(0);

      // ---- online softmax (q lane-local along columns) ----
      bool diag = (kv0 + KVB > q0w);
#pragma unroll
      for (int m = 0; m < 2; ++m) {
        int qg = q0w + m * 16 + lq;
        float sv[4][4];
        float vmax = -1e30f;
#pragma unroll
        for (int n = 0; n < 4; ++n)
#pragma unroll
          for (int r = 0; r < 4; ++r) {
            float xv = sc[n][m][r] * c1;
            if (diag && (kv0 + n * 16 + lk * 4 + r > qg)) xv = -1e30f;
            sv[n][r] = xv;
            vmax = fmaxf(vmax, xv);
          }
        vmax = fmaxf(vmax, __shfl_xor(vmax, 16));
        vmax = fmaxf(vmax, __shfl_xor(vmax, 32));
        float mnew = fmaxf(mrow[m], vmax);
        float cr = exp2f(mrow[m] - mnew);
        mrow[m] = mnew;
        float rs = 0.0f;
#pragma unroll
        for (int n = 0; n < 4; ++n)
#pragma unroll
          for (int r = 0; r < 4; ++r) {
            float pv = exp2f(sv[n][r] - mnew);
            sv[n][r] = pv;
            rs += pv;
          }
        rs += __shfl_xor(rs, 16);
        rs += __shfl_xor(rs, 32);
        lrow[m] = lrow[m] * cr + rs;

        // rescale O: gather cr from softmax-lane (lq=q) to output-lane (lk,r)
        float crr[4];
#pragma unroll
        for (int r = 0; r < 4; ++r) crr[r] = __shfl(cr, lk * 4 + r);
#pragma unroll
        for (int nd = 0; nd < 8; ++nd)
#pragma unroll
          for (int r = 0; r < 4; ++r) o_acc[m][nd][r] *= crr[r];

        // P -> wave-private LDS, packed bf16 pairs, b64 stores
        int qlocal = m * 16 + lq;
#pragma unroll
        for (int n = 0; n < 4; ++n) {
          uint2 pk_;
          pk_.x = cvt_pk_bf16(sv[n][0], sv[n][1]);
          pk_.y = cvt_pk_bf16(sv[n][2], sv[n][3]);
          int addr = qlocal * 128 + ((n * 32 + lk * 8) ^ ((qlocal & 7) << 4));
          *(uint2*)(&Ps[w][addr]) = pk_;
        }
      }

      // ---- PV ----
      __builtin_amdgcn_s_setprio(1);
#pragma unroll
      for (int ks = 0; ks < 2; ++ks) {
        bf16x8 pa[2];
#pragma unroll
        for (int m = 0; m < 2; ++m) {
          int row = m * 16 + lq;
          int addr = row * 128 + ((ks * 64 + lk * 16) ^ ((row & 7) << 4));
          pa[m] = *(const bf16x8*)(&Ps[w][addr]);
        }
#pragma unroll
        for (int nd = 0; nd < 8; ++nd) {
          int row = nd * 16 + lq;
          int addr = row * 128 + ((ks * 64 + lk * 16) ^ ((row & 7) << 4));
          bf16x8 vf = *(const bf16x8*)(&Vs[cur][addr]);
#pragma unroll
          for (int m = 0; m < 2; ++m)
            o_acc[m][nd] = __builtin_amdgcn_mfma_f32_16x16x32_bf16(pa[m], vf, o_acc[m][nd], 0, 0, 0);
        }
      }
      __builtin_amdgcn_s_setprio(0);
    }
    __syncthreads();
    cur ^= 1;
  }

  // ---- epilogue: O/l -> bf16 [BS][NH*D] ----
#pragma unroll
  for (int m = 0; m < 2; ++m)
#pragma unroll
    for (int r = 0; r < 4; ++r) {
      float lv = __shfl(lrow[m], lk * 4 + r);
      float rl = 1.0f / lv;
      int qg = q0w + m * 16 + lk * 4 + r;
      size_t base = ((size_t)b * S_ + qg) * (NH_ * D_) + h * D_;
#pragma unroll
      for (int nd = 0; nd < 8; ++nd)
        Ob[base + nd * 16 + lq] = f2bf(o_acc[m][nd][r] * rl);
    }
}

// ---------------------------------------------------------------------------
extern "C" void kernel_launch(void* const* d_in, const int* in_sizes, int n_in,
                              void* d_out, int out_size, void* d_ws, size_t ws_size,
                              hipStream_t stream) {
  const float* hs    = (const float*)d_in[0];
  const int*   pos   = (const int*)d_in[1];
  const float* w_qkv = (const float*)d_in[2];
  const float* w_o   = (const float*)d_in[3];
  const float* qw    = (const float*)d_in[4];
  const float* kw    = (const float*)d_in[5];
  float* out = (float*)d_out;

  char* ws = (char*)d_ws;
  unsigned short* Xbf  = (unsigned short*)ws;                         // 16 MB
  unsigned short* Wqbf = Xbf + (size_t)BS_ * H_;                      // 16 MB
  unsigned short* Wobf = Wqbf + (size_t)QKVO_ * H_;                   // 8 MB
  float* qkv = (float*)(Wobf + (size_t)H_ * (NH_ * D_));              // 64 MB
  unsigned short* Qb  = (unsigned short*)(qkv + (size_t)BS_ * QKVO_); // 16 MB
  unsigned short* Kb  = Qb + (size_t)B_ * NH_ * S_ * D_;              // 8 MB
  unsigned short* Vtb = Kb + (size_t)B_ * NKV_ * S_ * D_;             // 8 MB
  unsigned short* Ab  = Vtb + (size_t)B_ * NKV_ * S_ * D_;            // 16 MB

  // 1. converts
  k_f32_to_bf16<<<(BS_ * H_ / 4) / 256, 256, 0, stream>>>(hs, Xbf, BS_ * H_ / 4);
  k_f32_to_bf16<<<(QKVO_ * H_ / 4) / 256, 256, 0, stream>>>(w_qkv, Wqbf, QKVO_ * H_ / 4);
  k_f32_to_bf16<<<(H_ * NH_ * D_ / 4) / 256, 256, 0, stream>>>(w_o, Wobf, H_ * NH_ * D_ / 4);

  // 2. QKV GEMM: [4096,2048] x [4096,2048]^T -> [4096,4096] fp32
  k_gemm_bf16<<<(BS_ / BM) * (QKVO_ / BN), 256, 0, stream>>>(
      Xbf, Wqbf, qkv, BS_, QKVO_, H_);

  // 3. RMSNorm + RoPE for q,k
  k_norm_rope<<<BS_ * 24 / 4, 256, 0, stream>>>(qkv, pos, qw, kw, Qb, Kb);

  // 4. V convert+transpose
  k_v_transpose<<<B_ * NKV_ * (S_ / 64), 256, 0, stream>>>(qkv, Vtb);

  // 5. causal GQA flash attention (uniform-load 8-wave blocks)
  k_attn<<<256, 512, 0, stream>>>(Qb, Kb, Vtb, Ab);

  // 6. output GEMM: [4096,2048] x [2048,2048]^T -> d_out fp32
  k_gemm_bf16<<<(BS_ / BM) * (H_ / BN), 256, 0, stream>>>(
      Ab, Wobf, out, BS_, H_, H_);
}